// Round 13
// baseline (64.328 us; speedup 1.0000x reference)
//
#include <hip/hip_runtime.h>
#include <cfloat>
#include <climits>

#define B_   8
#define N1_  1024
#define N2_  4096
#define C_   256
#define TPQ  16                 // threads per query
#define QPB  (256 / TPQ)        // 16 queries per block
#define REP  3                  // instrument: scan+merge repeated 3x

// ---------------------------------------------------------------------------
// Kernel 1: 3-NN search — round-2 logic, scan+merge wrapped in a 3x repeat
// (INSTRUMENT ROUND: forces knn into rocprof's top-5 with real counters;
//  output is byte-identical: every rep computes the same result from the
//  same inputs; LICM is defeated by an opaque register seed).
// ---------------------------------------------------------------------------

__device__ __forceinline__ bool better_(float d, int i, float D, int I) {
    return (d < D) || (d == D && i < I);   // lexicographic (d, index)
}

__device__ __forceinline__ void ins_(float d, int i,
                                     float& d0, float& d1, float& d2,
                                     int& i0, int& i1, int& i2) {
    if (better_(d, i, d2, i2)) {
        d2 = d; i2 = i;
        if (better_(d2, i2, d1, i1)) {
            float td = d1; d1 = d2; d2 = td;
            int   ti = i1; i1 = i2; i2 = ti;
            if (better_(d1, i1, d0, i0)) {
                td = d0; d0 = d1; d1 = td;
                ti = i0; i0 = i1; i1 = ti;
            }
        }
    }
}

__global__ __launch_bounds__(256) void knn_kernel(
    const float* __restrict__ p1, const float* __restrict__ p2,
    int4* __restrict__ wsi, float4* __restrict__ wsw) {
    __shared__ float4 pts[N1_];   // (2x, 2y, 2z, |p1|^2): 16 KB

    const int tid   = threadIdx.x;
    const int b     = blockIdx.x >> 8;     // N2/QPB = 256 tiles per batch
    const int mtile = blockIdx.x & 255;

    for (int j = tid; j < N1_; j += 256) {
        float x = p1[((size_t)b * N1_ + j) * 3 + 0];
        float y = p1[((size_t)b * N1_ + j) * 3 + 1];
        float z = p1[((size_t)b * N1_ + j) * 3 + 2];
        float s1 = __fadd_rn(__fadd_rn(__fmul_rn(x, x), __fmul_rn(y, y)),
                             __fmul_rn(z, z));
        pts[j] = make_float4(x + x, y + y, z + z, s1);  // 2x exact
    }
    __syncthreads();

    const int q = tid >> 4;       // query within tile
    const int t = tid & 15;       // sub-thread within query
    const int m = mtile * QPB + q;

    const size_t pbase = ((size_t)b * N2_ + m) * 3;
    const float x2 = p2[pbase + 0];
    const float y2 = p2[pbase + 1];
    const float z2 = p2[pbase + 2];
    const float s2 = __fadd_rn(__fadd_rn(__fmul_rn(x2, x2), __fmul_rn(y2, y2)),
                               __fmul_rn(z2, z2));

    float rd0 = 0.f, rd1 = 0.f, rd2 = 0.f;
    int   ri0 = 0,   ri1 = 0,   ri2 = 0;

    const float initf = FLT_MAX;
#pragma unroll 1
    for (int rep = 0; rep < REP; ++rep) {
        // Opaque copy of FLT_MAX: compiler can't prove loop-invariance of the
        // scan dataflow -> scan+merge must execute every rep (no LICM/DCE).
        float seed;
        asm volatile("v_mov_b32 %0, %1" : "=v"(seed) : "v"(initf));
        float d0 = seed, d1 = seed, d2 = seed;
        int   i0 = INT_MAX, i1 = INT_MAX, i2 = INT_MAX;

#pragma unroll 4
        for (int n = t; n < N1_; n += TPQ) {
            float4 p = pts[n];
            // dot2 == 2*dot bit-exactly (x2 scaling commutes with RN)
            float dot2 = __fadd_rn(__fadd_rn(__fmul_rn(x2, p.x),
                                             __fmul_rn(y2, p.y)),
                                   __fmul_rn(z2, p.z));
            float dd = __fadd_rn(__fsub_rn(s2, dot2), p.w);

            bool c0 = dd < d0;
            bool c1 = dd < d1;
            bool c2 = dd < d2;
            float n0 = fminf(dd, d0);
            float n1 = __builtin_amdgcn_fmed3f(dd, d0, d1);
            float n2 = __builtin_amdgcn_fmed3f(dd, d1, d2);
            int j0 = c0 ? n : i0;
            int j1 = c1 ? (c0 ? i0 : n) : i1;
            int j2 = c2 ? (c1 ? i1 : n) : i2;
            d0 = n0; d1 = n1; d2 = n2;
            i0 = j0; i1 = j1; i2 = j2;
        }

        for (int mask = 1; mask < TPQ; mask <<= 1) {
            float pd0 = __shfl_xor(d0, mask, TPQ);
            float pd1 = __shfl_xor(d1, mask, TPQ);
            float pd2 = __shfl_xor(d2, mask, TPQ);
            int   pi0 = __shfl_xor(i0, mask, TPQ);
            int   pi1 = __shfl_xor(i1, mask, TPQ);
            int   pi2 = __shfl_xor(i2, mask, TPQ);
            ins_(pd0, pi0, d0, d1, d2, i0, i1, i2);
            ins_(pd1, pi1, d0, d1, d2, i0, i1, i2);
            ins_(pd2, pi2, d0, d1, d2, i0, i1, i2);
        }

        // Sink each rep's results (keeps them live; no cost).
        asm volatile("" :: "v"(d0), "v"(d1), "v"(d2),
                           "v"(i0), "v"(i1), "v"(i2));
        rd0 = d0; rd1 = d1; rd2 = d2;
        ri0 = i0; ri1 = i1; ri2 = i2;
    }

    if (t == 0) {
        float r0 = 1.0f / __fadd_rn(rd0, 1e-8f);
        float r1 = 1.0f / __fadd_rn(rd1, 1e-8f);
        float r2 = 1.0f / __fadd_rn(rd2, 1e-8f);
        float s  = __fadd_rn(__fadd_rn(r0, r1), r2);
        const size_t o = (size_t)b * N2_ + m;
        wsi[o] = make_int4(ri0, ri1, ri2, 0);
        wsw[o] = make_float4(r0 / s, r1 / s, r2 / s, 0.0f);
    }
}

// ---------------------------------------------------------------------------
// Kernel 2 (v4): gather + blend — byte-exact round-6 version (control).
// ---------------------------------------------------------------------------

__global__ __launch_bounds__(256) void blend_kernel(
    const float* __restrict__ x1, const int4* __restrict__ wsi,
    const float4* __restrict__ wsw, float* __restrict__ out) {
    __shared__ float4 L4[N1_];   // 16 KB, XOR-swizzled channel-interleaved

    int bid = blockIdx.x;
    const int mhalf = bid & 1;
    const int ct    = (bid >> 1) & 63;   // 64 channel tiles of 4
    const int b     = bid >> 7;
    const int tid   = threadIdx.x;

    // Prefetch idx/weights for all 8 m-iterations.
    const size_t wbase = (size_t)b * N2_ + (size_t)mhalf * 2048;
    int4   id[8];
    float4 w[8];
#pragma unroll
    for (int mb = 0; mb < 8; ++mb) {
        id[mb] = wsi[wbase + mb * 256 + tid];
        w[mb]  = wsw[wbase + mb * 256 + tid];
    }

    // Stage 4 channels, register-transposed into interleaved LDS.
    const float* src = x1 + ((size_t)b * C_ + (size_t)ct * 4) * N1_;
    float4 v[4];
#pragma unroll
    for (int c = 0; c < 4; ++c)
        v[c] = reinterpret_cast<const float4*>(src + (size_t)c * N1_)[tid];
#pragma unroll
    for (int e = 0; e < 4; ++e) {
        const int n = 4 * tid + e;
        L4[n ^ ((n >> 3) & 7)] = make_float4((&v[0].x)[e], (&v[1].x)[e],
                                             (&v[2].x)[e], (&v[3].x)[e]);
    }
    __syncthreads();

    const size_t obase = ((size_t)b * C_ + (size_t)ct * 4) * N2_;
#pragma unroll
    for (int mb = 0; mb < 8; ++mb) {
        const int m = mhalf * 2048 + mb * 256 + tid;
        const int na = id[mb].x, nb = id[mb].y, nc = id[mb].z;
        const float4 A  = L4[na ^ ((na >> 3) & 7)];
        const float4 Bv = L4[nb ^ ((nb >> 3) & 7)];
        const float4 Cv = L4[nc ^ ((nc >> 3) & 7)];
        const float wx = w[mb].x, wy = w[mb].y, wz = w[mb].z;
#pragma unroll
        for (int r = 0; r < 4; ++r) {
            float acc = __fadd_rn(__fadd_rn(__fmul_rn((&A.x)[r],  wx),
                                            __fmul_rn((&Bv.x)[r], wy)),
                                  __fmul_rn((&Cv.x)[r], wz));
            __builtin_nontemporal_store(acc, &out[obase + (size_t)r * N2_ + m]);
        }
    }
}

extern "C" void kernel_launch(void* const* d_in, const int* in_sizes, int n_in,
                              void* d_out, int out_size, void* d_ws, size_t ws_size,
                              hipStream_t stream) {
    const float* p1 = (const float*)d_in[0];   // [B, N1, 3]
    const float* x1 = (const float*)d_in[1];   // [B, C, N1]
    const float* p2 = (const float*)d_in[2];   // [B, N2, 3]
    float* out = (float*)d_out;                // [B, C, N2]

    int4*   wsi = (int4*)d_ws;
    float4* wsw = (float4*)((char*)d_ws + (size_t)B_ * N2_ * sizeof(int4));

    knn_kernel<<<B_ * (N2_ / QPB), 256, 0, stream>>>(p1, p2, wsi, wsw);
    blend_kernel<<<B_ * (C_ / 4) * 2, 256, 0, stream>>>(x1, wsi, wsw, out);
}

// Round 14
// 32.009 us; speedup vs baseline: 2.0097x; 2.0097x over previous
//
#include <hip/hip_runtime.h>
#include <cfloat>
#include <climits>

#define B_   8
#define N1_  1024
#define N2_  4096
#define C_   256
#define TPQ  16                 // threads (lanes) per query
#define QPB  (256 / TPQ)        // 16 queries per block

__device__ __forceinline__ unsigned umin_(unsigned a, unsigned b) { return a < b ? a : b; }

// Guaranteed single-op median-of-3 (u32). VOP3, all-VGPR operands.
__device__ __forceinline__ unsigned umed3_(unsigned a, unsigned b, unsigned c) {
    unsigned d;
    asm("v_med3_u32 %0, %1, %2, %3" : "=v"(d) : "v"(a), "v"(b), "v"(c));
    return d;
}

// Sorted-quad insert (invariant k0<=k1<=k2<=k3): min + 3x med3 = 4 VALU ops.
// med3(k, k_{i-1}, k_i) == max(k_{i-1}, min(k, k_i)) given the invariant.
#define KINS4(k, k0, k1, k2, k3) do {                 \
    unsigned _n1 = umed3_((k), k0, k1);               \
    unsigned _n2 = umed3_((k), k1, k2);               \
    unsigned _n3 = umed3_((k), k2, k3);               \
    k0 = umin_((k), k0);  k1 = _n1;  k2 = _n2;  k3 = _n3; \
} while (0)

// ---------------------------------------------------------------------------
// Kernel 1 (v9): 3-NN. R2's validated mapping (16 lanes/query, 2048 blocks)
// with the R9/R10-validated trunc-key top-4 + exact-rescue selection,
// realized in minimal VALU ops:
//   per eval: 7 (exact ref-order dist) + 1 (v_max_f32) + 1 (v_and_or_b32)
//             + 4 (med3 KINS4)  ~= 13 ops  (was ~18)
// key = (bits(max(dd,0)) & ~1023) | n  -> u32 order == (trunc dist, idx).
// Rescue recomputes the kept 4 dists EXACTLY (reference bit order), exact
// (d,idx) sort-4, takes 3 -> output bit-identical when selection set correct.
// ---------------------------------------------------------------------------
__global__ __launch_bounds__(256) void knn_kernel(
    const float* __restrict__ p1, const float* __restrict__ p2,
    int4* __restrict__ wsi, float4* __restrict__ wsw) {
    __shared__ float4 pts[N1_];   // (2x, 2y, 2z, |p1|^2): 16 KB

    const int tid   = threadIdx.x;
    const int b     = blockIdx.x >> 8;     // 256 query-tiles per batch
    const int mtile = blockIdx.x & 255;

    for (int j = tid; j < N1_; j += 256) {
        float x = p1[((size_t)b * N1_ + j) * 3 + 0];
        float y = p1[((size_t)b * N1_ + j) * 3 + 1];
        float z = p1[((size_t)b * N1_ + j) * 3 + 2];
        float s1 = __fadd_rn(__fadd_rn(__fmul_rn(x, x), __fmul_rn(y, y)),
                             __fmul_rn(z, z));
        pts[j] = make_float4(x + x, y + y, z + z, s1);  // 2x exact under RN
    }
    __syncthreads();

    const int q = tid >> 4;       // query within tile
    const int t = tid & 15;       // lane within query group
    const int m = mtile * QPB + q;

    const size_t pbase = ((size_t)b * N2_ + m) * 3;
    const float x2 = p2[pbase + 0];
    const float y2 = p2[pbase + 1];
    const float z2 = p2[pbase + 2];
    const float s2 = __fadd_rn(__fadd_rn(__fmul_rn(x2, x2), __fmul_rn(y2, y2)),
                               __fmul_rn(z2, z2));

    unsigned k0 = UINT_MAX, k1 = UINT_MAX, k2 = UINT_MAX, k3 = UINT_MAX;

#pragma unroll 4
    for (int n = t; n < N1_; n += TPQ) {
        float4 p = pts[n];
        // dot2 == 2*dot bit-exactly (pre-doubled coords commute with RN)
        float dot2 = __fadd_rn(__fadd_rn(__fmul_rn(x2, p.x), __fmul_rn(y2, p.y)),
                               __fmul_rn(z2, p.z));
        float dd = __fadd_rn(__fsub_rn(s2, dot2), p.w);
        unsigned key = (__float_as_uint(fmaxf(dd, 0.f)) & 0xFFFFFC00u)
                       | (unsigned)n;                    // v_max + v_and_or
        KINS4(key, k0, k1, k2, k3);
    }

    // Butterfly-merge the 16 lanes' top-4 keys (u32 order, exact).
    for (int mask = 1; mask < TPQ; mask <<= 1) {
        unsigned p0 = (unsigned)__shfl_xor((int)k0, mask, TPQ);
        unsigned p1_ = (unsigned)__shfl_xor((int)k1, mask, TPQ);
        unsigned p2_ = (unsigned)__shfl_xor((int)k2, mask, TPQ);
        unsigned p3_ = (unsigned)__shfl_xor((int)k3, mask, TPQ);
        KINS4(p0,  k0, k1, k2, k3);
        KINS4(p1_, k0, k1, k2, k3);
        KINS4(p2_, k0, k1, k2, k3);
        KINS4(p3_, k0, k1, k2, k3);
    }

    if (t == 0) {
        int   ix[4];
        float dx[4];
#pragma unroll
        for (int k = 0; k < 4; ++k) {
            const unsigned a = k == 0 ? k0 : k == 1 ? k1 : k == 2 ? k2 : k3;
            const int n = (int)(a & 1023u);
            const float4 c = pts[n];
            // EXACT reference arithmetic: dd = (s2 - dot2) + s1
            dx[k] = __fadd_rn(__fsub_rn(s2,
                __fadd_rn(__fadd_rn(__fmul_rn(x2, c.x), __fmul_rn(y2, c.y)),
                          __fmul_rn(z2, c.z))), c.w);
            ix[k] = n;
        }
        // Exact lexicographic (d, idx) sort-4: (0,1)(2,3)(0,2)(1,3)(1,2)
#define CSWAP(a, b) do {                                            \
        bool sw = (dx[b] < dx[a]) || (dx[b] == dx[a] && ix[b] < ix[a]); \
        float td = sw ? dx[b] : dx[a]; dx[b] = sw ? dx[a] : dx[b]; dx[a] = td; \
        int   ti = sw ? ix[b] : ix[a]; ix[b] = sw ? ix[a] : ix[b]; ix[a] = ti; \
    } while (0)
        CSWAP(0, 1); CSWAP(2, 3); CSWAP(0, 2); CSWAP(1, 3); CSWAP(1, 2);
#undef CSWAP

        const float r0 = 1.0f / __fadd_rn(dx[0], 1e-8f);
        const float r1 = 1.0f / __fadd_rn(dx[1], 1e-8f);
        const float r2 = 1.0f / __fadd_rn(dx[2], 1e-8f);
        const float s  = __fadd_rn(__fadd_rn(r0, r1), r2);
        const size_t o = (size_t)b * N2_ + m;
        wsi[o] = make_int4(ix[0], ix[1], ix[2], 0);
        wsw[o] = make_float4(r0 / s, r1 / s, r2 / s, 0.0f);
    }
}

// ---------------------------------------------------------------------------
// Kernel 2 (v4): gather + blend — byte-exact round-6 version (control).
// ---------------------------------------------------------------------------

__global__ __launch_bounds__(256) void blend_kernel(
    const float* __restrict__ x1, const int4* __restrict__ wsi,
    const float4* __restrict__ wsw, float* __restrict__ out) {
    __shared__ float4 L4[N1_];   // 16 KB, XOR-swizzled channel-interleaved

    int bid = blockIdx.x;
    const int mhalf = bid & 1;
    const int ct    = (bid >> 1) & 63;   // 64 channel tiles of 4
    const int b     = bid >> 7;
    const int tid   = threadIdx.x;

    // Prefetch idx/weights for all 8 m-iterations.
    const size_t wbase = (size_t)b * N2_ + (size_t)mhalf * 2048;
    int4   id[8];
    float4 w[8];
#pragma unroll
    for (int mb = 0; mb < 8; ++mb) {
        id[mb] = wsi[wbase + mb * 256 + tid];
        w[mb]  = wsw[wbase + mb * 256 + tid];
    }

    // Stage 4 channels, register-transposed into interleaved LDS.
    const float* src = x1 + ((size_t)b * C_ + (size_t)ct * 4) * N1_;
    float4 v[4];
#pragma unroll
    for (int c = 0; c < 4; ++c)
        v[c] = reinterpret_cast<const float4*>(src + (size_t)c * N1_)[tid];
#pragma unroll
    for (int e = 0; e < 4; ++e) {
        const int n = 4 * tid + e;
        L4[n ^ ((n >> 3) & 7)] = make_float4((&v[0].x)[e], (&v[1].x)[e],
                                             (&v[2].x)[e], (&v[3].x)[e]);
    }
    __syncthreads();

    const size_t obase = ((size_t)b * C_ + (size_t)ct * 4) * N2_;
#pragma unroll
    for (int mb = 0; mb < 8; ++mb) {
        const int m = mhalf * 2048 + mb * 256 + tid;
        const int na = id[mb].x, nb = id[mb].y, nc = id[mb].z;
        const float4 A  = L4[na ^ ((na >> 3) & 7)];
        const float4 Bv = L4[nb ^ ((nb >> 3) & 7)];
        const float4 Cv = L4[nc ^ ((nc >> 3) & 7)];
        const float wx = w[mb].x, wy = w[mb].y, wz = w[mb].z;
#pragma unroll
        for (int r = 0; r < 4; ++r) {
            float acc = __fadd_rn(__fadd_rn(__fmul_rn((&A.x)[r],  wx),
                                            __fmul_rn((&Bv.x)[r], wy)),
                                  __fmul_rn((&Cv.x)[r], wz));
            __builtin_nontemporal_store(acc, &out[obase + (size_t)r * N2_ + m]);
        }
    }
}

extern "C" void kernel_launch(void* const* d_in, const int* in_sizes, int n_in,
                              void* d_out, int out_size, void* d_ws, size_t ws_size,
                              hipStream_t stream) {
    const float* p1 = (const float*)d_in[0];   // [B, N1, 3]
    const float* x1 = (const float*)d_in[1];   // [B, C, N1]
    const float* p2 = (const float*)d_in[2];   // [B, N2, 3]
    float* out = (float*)d_out;                // [B, C, N2]

    int4*   wsi = (int4*)d_ws;
    float4* wsw = (float4*)((char*)d_ws + (size_t)B_ * N2_ * sizeof(int4));

    knn_kernel<<<B_ * (N2_ / QPB), 256, 0, stream>>>(p1, p2, wsi, wsw);
    blend_kernel<<<B_ * (C_ / 4) * 2, 256, 0, stream>>>(x1, wsi, wsw, out);
}

// Round 15
// 29.608 us; speedup vs baseline: 2.1726x; 1.0811x over previous
//
#include <hip/hip_runtime.h>
#include <cfloat>
#include <climits>

#define B_   8
#define N1_  1024
#define N2_  4096
#define C_   256
#define TPQ  16                 // lanes per query
#define QPB  (256 / TPQ)        // 16 queries per block

typedef float vf2 __attribute__((ext_vector_type(2)));

__device__ __forceinline__ unsigned umin_(unsigned a, unsigned b) { return a < b ? a : b; }

// Guaranteed single-op median-of-3 (u32). VOP3, all-VGPR operands.
__device__ __forceinline__ unsigned umed3_(unsigned a, unsigned b, unsigned c) {
    unsigned d;
    asm("v_med3_u32 %0, %1, %2, %3" : "=v"(d) : "v"(a), "v"(b), "v"(c));
    return d;
}

// Sorted-quad insert (invariant k0<=k1<=k2<=k3): min + 3x med3 = 4 VALU ops.
#define KINS4(k, k0, k1, k2, k3) do {                 \
    unsigned _n1 = umed3_((k), k0, k1);               \
    unsigned _n2 = umed3_((k), k1, k2);               \
    unsigned _n3 = umed3_((k), k2, k3);               \
    k0 = umin_((k), k0);  k1 = _n1;  k2 = _n2;  k3 = _n3; \
} while (0)

// ---------------------------------------------------------------------------
// Kernel 1 (v10): 3-NN. R14's validated selection (trunc-key top-4 + exact
// rescue) with R3's validated pair-interleaved packed-fp32 distance math:
//   Q[k] = {2x[2k], 2x[2k+1], 2y[2k], 2y[2k+1]}
//   R[k] = {2z[2k], 2z[2k+1], s1[2k], s1[2k+1]}
//   dd(pair) = (s2 - ((qx*x2 + qy*y2) + rz*z2)) + rs   [pk ops, contract off,
//   bit-exact == scalar reference order; R3 HW-validated]
// per eval: 3.5 pk-dist + 1 max + 1 and_or + 4 KINS ~= 9.5 ops (was 13).
// ---------------------------------------------------------------------------
__global__ __launch_bounds__(256) void knn_kernel(
    const float* __restrict__ p1, const float* __restrict__ p2,
    int4* __restrict__ wsi, float4* __restrict__ wsw) {
#pragma clang fp contract(off)
    __shared__ float4 Q[N1_ / 2];   // 8 KB
    __shared__ float4 R[N1_ / 2];   // 8 KB

    const int tid   = threadIdx.x;
    const int b     = blockIdx.x >> 8;     // 256 query-tiles per batch
    const int mtile = blockIdx.x & 255;

    // Stage coarse points, pair-interleaved, exact pre-doubling (R3 layout).
    for (int k = tid; k < N1_ / 2; k += 256) {
        const float* pa = &p1[((size_t)b * N1_ + 2 * k) * 3];
        float xa = pa[0], ya = pa[1], za = pa[2];
        float xb = pa[3], yb = pa[4], zb = pa[5];
        float sa = __fadd_rn(__fadd_rn(__fmul_rn(xa, xa), __fmul_rn(ya, ya)),
                             __fmul_rn(za, za));
        float sb = __fadd_rn(__fadd_rn(__fmul_rn(xb, xb), __fmul_rn(yb, yb)),
                             __fmul_rn(zb, zb));
        Q[k] = make_float4(xa + xa, xb + xb, ya + ya, yb + yb);
        R[k] = make_float4(za + za, zb + zb, sa, sb);
    }
    __syncthreads();

    const int q = tid >> 4;       // query within tile
    const int t = tid & 15;       // lane within query group
    const int m = mtile * QPB + q;

    const size_t pbase = ((size_t)b * N2_ + m) * 3;
    const float x2 = p2[pbase + 0];
    const float y2 = p2[pbase + 1];
    const float z2 = p2[pbase + 2];
    const float s2 = __fadd_rn(__fadd_rn(__fmul_rn(x2, x2), __fmul_rn(y2, y2)),
                               __fmul_rn(z2, z2));

    const vf2 x2v = {x2, x2};
    const vf2 y2v = {y2, y2};
    const vf2 z2v = {z2, z2};
    const vf2 s2v = {s2, s2};

    unsigned k0 = UINT_MAX, k1 = UINT_MAX, k2 = UINT_MAX, k3 = UINT_MAX;

    // 32 pair-iterations: candidates (2k, 2k+1), k = t + 16*j.
#pragma unroll 4
    for (int j = 0; j < N1_ / (2 * TPQ); ++j) {
        const int k = t + TPQ * j;
        float4 qv = Q[k];
        float4 rv = R[k];
        vf2 qx = {qv.x, qv.y};
        vf2 qy = {qv.z, qv.w};
        vf2 rz = {rv.x, rv.y};
        vf2 rs = {rv.z, rv.w};
        vf2 t1 = qx * x2v;              // v_pk_mul_f32, exact RN
        vf2 t2 = qy * y2v;
        vf2 t3 = rz * z2v;
        vf2 dot2 = (t1 + t2) + t3;      // left-assoc == reference order
        vf2 dd = (s2v - dot2) + rs;
        const unsigned un = (unsigned)(2 * k);
        unsigned ka = (__float_as_uint(fmaxf(dd.x, 0.f)) & 0xFFFFFC00u) | un;
        unsigned kb = (__float_as_uint(fmaxf(dd.y, 0.f)) & 0xFFFFFC00u) | (un + 1u);
        KINS4(ka, k0, k1, k2, k3);
        KINS4(kb, k0, k1, k2, k3);
    }

    // Butterfly-merge the 16 lanes' top-4 keys (u32 order, exact).
    for (int mask = 1; mask < TPQ; mask <<= 1) {
        unsigned p0 = (unsigned)__shfl_xor((int)k0, mask, TPQ);
        unsigned p1_ = (unsigned)__shfl_xor((int)k1, mask, TPQ);
        unsigned p2_ = (unsigned)__shfl_xor((int)k2, mask, TPQ);
        unsigned p3_ = (unsigned)__shfl_xor((int)k3, mask, TPQ);
        KINS4(p0,  k0, k1, k2, k3);
        KINS4(p1_, k0, k1, k2, k3);
        KINS4(p2_, k0, k1, k2, k3);
        KINS4(p3_, k0, k1, k2, k3);
    }

    if (t == 0) {
        int   ix[4];
        float dx[4];
#pragma unroll
        for (int k = 0; k < 4; ++k) {
            const unsigned a = k == 0 ? k0 : k == 1 ? k1 : k == 2 ? k2 : k3;
            const int n  = (int)(a & 1023u);
            const int kk = n >> 1;
            const int h  = n & 1;
            const float cx = h ? Q[kk].y : Q[kk].x;   // 2x
            const float cy = h ? Q[kk].w : Q[kk].z;   // 2y
            const float cz = h ? R[kk].y : R[kk].x;   // 2z
            const float cs = h ? R[kk].w : R[kk].z;   // s1
            // EXACT reference arithmetic: dd = (s2 - dot2) + s1
            dx[k] = __fadd_rn(__fsub_rn(s2,
                __fadd_rn(__fadd_rn(__fmul_rn(x2, cx), __fmul_rn(y2, cy)),
                          __fmul_rn(z2, cz))), cs);
            ix[k] = n;
        }
        // Exact lexicographic (d, idx) sort-4: (0,1)(2,3)(0,2)(1,3)(1,2)
#define CSWAP(a, b) do {                                            \
        bool sw = (dx[b] < dx[a]) || (dx[b] == dx[a] && ix[b] < ix[a]); \
        float td = sw ? dx[b] : dx[a]; dx[b] = sw ? dx[a] : dx[b]; dx[a] = td; \
        int   ti = sw ? ix[b] : ix[a]; ix[b] = sw ? ix[a] : ix[b]; ix[a] = ti; \
    } while (0)
        CSWAP(0, 1); CSWAP(2, 3); CSWAP(0, 2); CSWAP(1, 3); CSWAP(1, 2);
#undef CSWAP

        const float r0 = 1.0f / __fadd_rn(dx[0], 1e-8f);
        const float r1 = 1.0f / __fadd_rn(dx[1], 1e-8f);
        const float r2 = 1.0f / __fadd_rn(dx[2], 1e-8f);
        const float s  = __fadd_rn(__fadd_rn(r0, r1), r2);
        const size_t o = (size_t)b * N2_ + m;
        wsi[o] = make_int4(ix[0], ix[1], ix[2], 0);
        wsw[o] = make_float4(r0 / s, r1 / s, r2 / s, 0.0f);
    }
}

// ---------------------------------------------------------------------------
// Kernel 2 (v4): gather + blend — byte-exact round-6 version (control).
// ---------------------------------------------------------------------------

__global__ __launch_bounds__(256) void blend_kernel(
    const float* __restrict__ x1, const int4* __restrict__ wsi,
    const float4* __restrict__ wsw, float* __restrict__ out) {
    __shared__ float4 L4[N1_];   // 16 KB, XOR-swizzled channel-interleaved

    int bid = blockIdx.x;
    const int mhalf = bid & 1;
    const int ct    = (bid >> 1) & 63;   // 64 channel tiles of 4
    const int b     = bid >> 7;
    const int tid   = threadIdx.x;

    // Prefetch idx/weights for all 8 m-iterations.
    const size_t wbase = (size_t)b * N2_ + (size_t)mhalf * 2048;
    int4   id[8];
    float4 w[8];
#pragma unroll
    for (int mb = 0; mb < 8; ++mb) {
        id[mb] = wsi[wbase + mb * 256 + tid];
        w[mb]  = wsw[wbase + mb * 256 + tid];
    }

    // Stage 4 channels, register-transposed into interleaved LDS.
    const float* src = x1 + ((size_t)b * C_ + (size_t)ct * 4) * N1_;
    float4 v[4];
#pragma unroll
    for (int c = 0; c < 4; ++c)
        v[c] = reinterpret_cast<const float4*>(src + (size_t)c * N1_)[tid];
#pragma unroll
    for (int e = 0; e < 4; ++e) {
        const int n = 4 * tid + e;
        L4[n ^ ((n >> 3) & 7)] = make_float4((&v[0].x)[e], (&v[1].x)[e],
                                             (&v[2].x)[e], (&v[3].x)[e]);
    }
    __syncthreads();

    const size_t obase = ((size_t)b * C_ + (size_t)ct * 4) * N2_;
#pragma unroll
    for (int mb = 0; mb < 8; ++mb) {
        const int m = mhalf * 2048 + mb * 256 + tid;
        const int na = id[mb].x, nb = id[mb].y, nc = id[mb].z;
        const float4 A  = L4[na ^ ((na >> 3) & 7)];
        const float4 Bv = L4[nb ^ ((nb >> 3) & 7)];
        const float4 Cv = L4[nc ^ ((nc >> 3) & 7)];
        const float wx = w[mb].x, wy = w[mb].y, wz = w[mb].z;
#pragma unroll
        for (int r = 0; r < 4; ++r) {
            float acc = __fadd_rn(__fadd_rn(__fmul_rn((&A.x)[r],  wx),
                                            __fmul_rn((&Bv.x)[r], wy)),
                                  __fmul_rn((&Cv.x)[r], wz));
            __builtin_nontemporal_store(acc, &out[obase + (size_t)r * N2_ + m]);
        }
    }
}

extern "C" void kernel_launch(void* const* d_in, const int* in_sizes, int n_in,
                              void* d_out, int out_size, void* d_ws, size_t ws_size,
                              hipStream_t stream) {
    const float* p1 = (const float*)d_in[0];   // [B, N1, 3]
    const float* x1 = (const float*)d_in[1];   // [B, C, N1]
    const float* p2 = (const float*)d_in[2];   // [B, N2, 3]
    float* out = (float*)d_out;                // [B, C, N2]

    int4*   wsi = (int4*)d_ws;
    float4* wsw = (float4*)((char*)d_ws + (size_t)B_ * N2_ * sizeof(int4));

    knn_kernel<<<B_ * (N2_ / QPB), 256, 0, stream>>>(p1, p2, wsi, wsw);
    blend_kernel<<<B_ * (C_ / 4) * 2, 256, 0, stream>>>(x1, wsi, wsw, out);
}